// Round 2
// baseline (10868.169 us; speedup 1.0000x reference)
//
#include <hip/hip_runtime.h>
#include <cstdint>
#include <cstddef>

#define B_  128
#define T_  256
#define IN_ 512
#define H_  512
#define C_  64
#define G4  2048   // 4*H

__device__ __forceinline__ float sigm(float x) {
    return 1.f / (1.f + __expf(-x));
}
__device__ __forceinline__ float tanh_f(float x) {
    float e = __expf(2.f * x);
    return 1.f - 2.f / (e + 1.f);
}

// Build gate-interleaved combined weights:
// Wc[j'][k], j' = 4*u+g (u=hidden unit, g in {i,f,g,o}); source row = g*512+u.
// k in [0,512) from W_ih, [512,1024) from W_hh. bc[j'] = b_ih[src]+b_hh[src].
__global__ __launch_bounds__(256) void prep_weights(
    const float* __restrict__ Wih, const float* __restrict__ Whh,
    const float* __restrict__ bih, const float* __restrict__ bhh,
    float* __restrict__ Wc, float* __restrict__ bc)
{
    int idx = blockIdx.x * 256 + threadIdx.x;      // over 2048*1024
    if (idx >= G4 * 1024) return;
    int jp = idx >> 10;        // 0..2047
    int k  = idx & 1023;
    int u = jp >> 2, g = jp & 3;
    int src = g * H_ + u;
    float v = (k < IN_) ? Wih[(size_t)src * IN_ + k]
                        : Whh[(size_t)src * H_ + (k - IN_)];
    Wc[idx] = v;
    if (k == 0) bc[jp] = bih[src] + bhh[src];
}

// Wavefront-fused LSTM step: blockIdx.z = layer; layer0 computes t=kstep,
// layer1 computes t=kstep-1 (uses hs0[t] and hs1[t-1], both done by the
// previous launch). gates[b,j'] = sum_k [x_t | h_{t-1}][b,k]*Wc[j',k] + bc.
// Tile 32 batch x 32 gate-cols, K=1024 in BK=64 chunks.
// Grid (64, 4, 2) = 512 WGs -> 2 WG/CU, 8 waves/CU.
__global__ __launch_bounds__(256) void lstm_step2(
    const float* __restrict__ x,     // [B, T, 512] network input
    float* __restrict__ hs0,         // [B, T, 512] layer-0 h sequence
    float* __restrict__ c0st,        // [B, 512]
    const float* __restrict__ Wc0,   // [2048, 1024]
    const float* __restrict__ bc0,
    float* __restrict__ hs1,         // [B, T, 512] layer-1 h sequence
    float* __restrict__ c1st,
    const float* __restrict__ Wc1,
    const float* __restrict__ bc1,
    int kstep)
{
    const int layer = blockIdx.z;
    const int t = kstep - layer;
    if (t < 0 || t >= T_) return;    // uniform across the WG

    const float* xin = layer ? hs0 : x;
    float* hseq      = layer ? hs1 : hs0;
    float* cst       = layer ? c1st : c0st;
    const float* Wc  = layer ? Wc1 : Wc0;
    const float* bc  = layer ? bc1 : bc0;

    __shared__ float Ast[64][34];    // [k][row] (even stride: 8B-aligned float2)
    __shared__ float Bst[64][34];    // [k][col]
    __shared__ float Gs[32][33];     // gate tile [row][col]

    const int tid = threadIdx.x;
    const int tx = tid & 15, ty = tid >> 4;
    const int n0 = blockIdx.x * 32;    // gate-col tile base
    const int b0 = blockIdx.y * 32;    // batch tile base

    float a00 = 0.f, a01 = 0.f, a10 = 0.f, a11 = 0.f;

    // staging: 8 threads per row, 2x float4 each -> 64 k-elems per row-chunk
    const int lr = tid >> 3;           // 0..31
    const int lk = (tid & 7) << 3;     // 0,8,...,56
    const int tprev = (t > 0) ? (t - 1) : 0;
    const float* xrow = xin  + ((size_t)(b0 + lr) * T_ + t) * IN_;
    const float* hrow = hseq + ((size_t)(b0 + lr) * T_ + tprev) * H_;
    const float* wrow = Wc + (size_t)(n0 + lr) * 1024;

    for (int k0 = 0; k0 < 1024; k0 += 64) {
        const int kk = k0 + lk;        // chunk is uniformly x-part or h-part
        float4 av0, av1;
        if (kk < IN_) {
            av0 = *(const float4*)(xrow + kk);
            av1 = *(const float4*)(xrow + kk + 4);
        } else if (t > 0) {
            av0 = *(const float4*)(hrow + (kk - IN_));
            av1 = *(const float4*)(hrow + (kk - IN_) + 4);
        } else {
            av0 = make_float4(0.f, 0.f, 0.f, 0.f);   // h_{-1} = 0
            av1 = av0;
        }
        float4 bv0 = *(const float4*)(wrow + kk);
        float4 bv1 = *(const float4*)(wrow + kk + 4);
        __syncthreads();   // previous chunk's reads done before overwrite
        Ast[lk + 0][lr] = av0.x; Ast[lk + 1][lr] = av0.y;
        Ast[lk + 2][lr] = av0.z; Ast[lk + 3][lr] = av0.w;
        Ast[lk + 4][lr] = av1.x; Ast[lk + 5][lr] = av1.y;
        Ast[lk + 6][lr] = av1.z; Ast[lk + 7][lr] = av1.w;
        Bst[lk + 0][lr] = bv0.x; Bst[lk + 1][lr] = bv0.y;
        Bst[lk + 2][lr] = bv0.z; Bst[lk + 3][lr] = bv0.w;
        Bst[lk + 4][lr] = bv1.x; Bst[lk + 5][lr] = bv1.y;
        Bst[lk + 6][lr] = bv1.z; Bst[lk + 7][lr] = bv1.w;
        __syncthreads();
        #pragma unroll
        for (int k = 0; k < 64; ++k) {
            float2 a = *(const float2*)&Ast[k][2 * ty];   // 16-lane broadcast
            float2 b = *(const float2*)&Bst[k][2 * tx];   // consecutive banks
            a00 += a.x * b.x; a01 += a.x * b.y;
            a10 += a.y * b.x; a11 += a.y * b.y;
        }
    }

    // gates (+bias) -> LDS for the per-unit exchange
    const float bx = bc[n0 + 2 * tx], by = bc[n0 + 2 * tx + 1];
    Gs[2 * ty + 0][2 * tx + 0] = a00 + bx;
    Gs[2 * ty + 0][2 * tx + 1] = a01 + by;
    Gs[2 * ty + 1][2 * tx + 0] = a10 + bx;
    Gs[2 * ty + 1][2 * tx + 1] = a11 + by;
    __syncthreads();

    // cell update: 32 rows x 8 hidden units = 256 threads, 1 each
    const int r = tid >> 3;        // batch row 0..31
    const int u = tid & 7;         // local unit 0..7
    const float gi = Gs[r][4 * u + 0];
    const float gf = Gs[r][4 * u + 1];
    const float gg = Gs[r][4 * u + 2];
    const float go = Gs[r][4 * u + 3];
    const float i_ = sigm(gi), f_ = sigm(gf), g_ = tanh_f(gg), o_ = sigm(go);
    const int bg = b0 + r;
    const int ug = (n0 >> 2) + u;          // global hidden unit
    const float cold = (t > 0) ? cst[bg * H_ + ug] : 0.f;
    const float cn = f_ * cold + i_ * g_;
    const float hn = o_ * tanh_f(cn);
    cst[bg * H_ + ug] = cn;
    hseq[((size_t)bg * T_ + t) * H_ + ug] = hn;
}

// logits[b,t,c] = sigmoid( dot(h1[b,t,:], Wl[c,:]) + bl[c] ), t < 255
// Rows m = b*255+t (32640 = 510*64 exactly). Tile 64 rows x 64 cols, K=512.
__global__ __launch_bounds__(256) void linear_sig(
    const float* __restrict__ h,    // hseq1 [B, T, 512]
    const float* __restrict__ Wl,   // [64, 512]
    const float* __restrict__ bl,   // [64]
    float* __restrict__ out)        // [B, 255, 64]
{
    __shared__ float Ast[32][68];   // [k][row], stride mult of 4 -> 16B-aligned float4
    __shared__ float Bst[32][68];   // [k][col]

    const int tid = threadIdx.x;
    const int tx = tid & 15, ty = tid >> 4;
    const int m0 = blockIdx.x * 64;

    float acc[4][4] = {};

    const int lr = tid >> 2;          // 0..63
    const int lk = (tid & 3) << 3;    // 0,8,16,24
    const int m = m0 + lr;
    const int b = m / 255, tt = m % 255;
    const float* arow = h + ((size_t)b * T_ + tt) * H_;
    const float* wrow = Wl + (size_t)lr * 512;

    for (int k0 = 0; k0 < 512; k0 += 32) {
        float4 a0 = *(const float4*)(arow + k0 + lk);
        float4 a1 = *(const float4*)(arow + k0 + lk + 4);
        float4 w0 = *(const float4*)(wrow + k0 + lk);
        float4 w1 = *(const float4*)(wrow + k0 + lk + 4);
        __syncthreads();
        Ast[lk + 0][lr] = a0.x; Ast[lk + 1][lr] = a0.y;
        Ast[lk + 2][lr] = a0.z; Ast[lk + 3][lr] = a0.w;
        Ast[lk + 4][lr] = a1.x; Ast[lk + 5][lr] = a1.y;
        Ast[lk + 6][lr] = a1.z; Ast[lk + 7][lr] = a1.w;
        Bst[lk + 0][lr] = w0.x; Bst[lk + 1][lr] = w0.y;
        Bst[lk + 2][lr] = w0.z; Bst[lk + 3][lr] = w0.w;
        Bst[lk + 4][lr] = w1.x; Bst[lk + 5][lr] = w1.y;
        Bst[lk + 6][lr] = w1.z; Bst[lk + 7][lr] = w1.w;
        __syncthreads();
        #pragma unroll
        for (int k = 0; k < 32; ++k) {
            float4 av = *(const float4*)&Ast[k][4 * ty];
            float4 wv = *(const float4*)&Bst[k][4 * tx];
            float ar[4] = {av.x, av.y, av.z, av.w};
            float wr[4] = {wv.x, wv.y, wv.z, wv.w};
            #pragma unroll
            for (int i = 0; i < 4; ++i)
                #pragma unroll
                for (int j = 0; j < 4; ++j)
                    acc[i][j] += ar[i] * wr[j];
        }
    }

    const float4 blv = *(const float4*)&bl[4 * tx];
    const float blr[4] = {blv.x, blv.y, blv.z, blv.w};
    #pragma unroll
    for (int i = 0; i < 4; ++i) {
        const int mg = m0 + 4 * ty + i;
        float4 o;
        o.x = sigm(acc[i][0] + blr[0]);
        o.y = sigm(acc[i][1] + blr[1]);
        o.z = sigm(acc[i][2] + blr[2]);
        o.w = sigm(acc[i][3] + blr[3]);
        *(float4*)&out[(size_t)mg * C_ + 4 * tx] = o;
    }
}

extern "C" void kernel_launch(void* const* d_in, const int* in_sizes, int n_in,
                              void* d_out, int out_size, void* d_ws, size_t ws_size,
                              hipStream_t stream)
{
    (void)in_sizes; (void)n_in; (void)out_size; (void)ws_size;

    const float* x    = (const float*)d_in[0];
    // d_in[1] = y (unused), d_in[2] = batch_size (unused)
    const float* Wih0 = (const float*)d_in[3];
    const float* Whh0 = (const float*)d_in[4];
    const float* bih0 = (const float*)d_in[5];
    const float* bhh0 = (const float*)d_in[6];
    const float* Wih1 = (const float*)d_in[7];
    const float* Whh1 = (const float*)d_in[8];
    const float* bih1 = (const float*)d_in[9];
    const float* bhh1 = (const float*)d_in[10];
    const float* Wlin = (const float*)d_in[11];
    const float* blin = (const float*)d_in[12];
    float* out = (float*)d_out;

    float* ws = (float*)d_ws;
    float* Wc0 = ws;  ws += (size_t)G4 * 1024;            // 8 MB
    float* Wc1 = ws;  ws += (size_t)G4 * 1024;            // 8 MB
    float* bc0 = ws;  ws += G4;
    float* bc1 = ws;  ws += G4;
    float* c0  = ws;  ws += (size_t)B_ * H_;              // 256 KB
    float* c1  = ws;  ws += (size_t)B_ * H_;
    float* hs0 = ws;  ws += (size_t)B_ * T_ * H_;         // 64 MB
    float* hs1 = ws;  ws += (size_t)B_ * T_ * H_;         // 64 MB
    // total ~150 MB

    prep_weights<<<8192, 256, 0, stream>>>(Wih0, Whh0, bih0, bhh0, Wc0, bc0);
    prep_weights<<<8192, 256, 0, stream>>>(Wih1, Whh1, bih1, bhh1, Wc1, bc1);

    // wavefront: launch k computes layer0 step k and layer1 step k-1
    const dim3 sg(64, 4, 2);
    for (int k = 0; k <= T_; ++k)
        lstm_step2<<<sg, 256, 0, stream>>>(x, hs0, c0, Wc0, bc0,
                                           hs1, c1, Wc1, bc1, k);

    linear_sig<<<510, 256, 0, stream>>>(hs1, Wlin, blin, out);
}

// Round 3
// 4298.825 us; speedup vs baseline: 2.5282x; 2.5282x over previous
//
#include <hip/hip_runtime.h>
#include <cstdint>
#include <cstddef>

#define B_  128
#define T_  256
#define IN_ 512
#define H_  512
#define C_  64
#define G4  2048   // 4*H

typedef __attribute__((ext_vector_type(8))) short short8;
typedef __attribute__((ext_vector_type(8))) __bf16 bf16x8_t;
typedef __attribute__((ext_vector_type(4))) float f32x4;

__device__ __forceinline__ float sigm(float x) { return 1.f / (1.f + __expf(-x)); }
__device__ __forceinline__ float tanh_f(float x) {
    float e = __expf(2.f * x);
    return 1.f - 2.f / (e + 1.f);
}
// fp32 -> bf16 round-to-nearest-even (values are bounded; no NaN handling needed)
__device__ __forceinline__ unsigned short f2bf(float f) {
    unsigned u = __float_as_uint(f);
    u = (u + 0x7fffu + ((u >> 16) & 1u)) >> 16;
    return (unsigned short)u;
}
__device__ __forceinline__ float bf2f(unsigned short s) {
    return __uint_as_float(((unsigned)s) << 16);
}
__device__ __forceinline__ bf16x8_t as_bf(short8 s) {
    union { short8 s; bf16x8_t b; } u; u.s = s; return u.b;
}

// LDS XOR swizzle on the k index (units of shorts; 16B granules within 128B rows)
#define SWZ(r, k) ((k) ^ (((r) & 7) << 3))

// Split combined weights into gate-interleaved bf16 hi/lo:
// Wc[j'=4u+g][k], src row = g*512+u; k<512 from W_ih, else W_hh.
__global__ __launch_bounds__(256) void prep_w(
    const float* __restrict__ Wih, const float* __restrict__ Whh,
    const float* __restrict__ bih, const float* __restrict__ bhh,
    short* __restrict__ Whi, short* __restrict__ Wlo, float* __restrict__ bc)
{
    int idx = blockIdx.x * 256 + threadIdx.x;     // over 2048*1024
    if (idx >= G4 * 1024) return;
    int jp = idx >> 10, k = idx & 1023;
    int u = jp >> 2, g = jp & 3;
    int src = g * H_ + u;
    float v = (k < IN_) ? Wih[(size_t)src * IN_ + k]
                        : Whh[(size_t)src * H_ + (k - IN_)];
    unsigned short hb = f2bf(v);
    Whi[idx] = (short)hb;
    Wlo[idx] = (short)f2bf(v - bf2f(hb));
    if (k == 0) bc[jp] = bih[src] + bhh[src];
}

// Wavefront-fused MFMA LSTM step. 512 WGs (2/CU), tile BM=32 x BN=32, K=1024
// (512 at t==0). Split-bf16 A and B, 3 MFMAs per 16x16x32 product.
// XCD swizzle: wg&7 = XCD; XCDs 0-3 -> layer0, 4-7 -> layer1; each XCD owns a
// contiguous 16-N-tile weight slice (2 MB -> L2-resident across launches).
__global__ __launch_bounds__(256) void lstm_step_mfma(
    const float* __restrict__ x,
    short* __restrict__ h0h, short* __restrict__ h0l,
    short* __restrict__ h1h, short* __restrict__ h1l,
    float* __restrict__ c0, float* __restrict__ c1,
    const short* __restrict__ W0h, const short* __restrict__ W0l,
    const short* __restrict__ W1h, const short* __restrict__ W1l,
    const float* __restrict__ bc0, const float* __restrict__ bc1,
    int kstep)
{
    const int wg = blockIdx.x;
    const int xcd = wg & 7, within = wg >> 3;     // 64 WGs per XCD
    const int layer = xcd >> 2;
    const int nt = (xcd & 3) * 16 + (within & 15);   // 0..63 gate-col tile
    const int mt = within >> 4;                       // 0..3 batch tile
    const int t = kstep - layer;
    if (t < 0 || t >= T_) return;

    const int n0 = nt * 32;     // gate-col base
    const int b0 = mt * 32;     // batch base

    const short* Wh = layer ? W1h : W0h;
    const short* Wl = layer ? W1l : W0l;
    const float* bcp = layer ? bc1 : bc0;
    float* cst = layer ? c1 : c0;

    __shared__ short Ah[32][64], Al[32][64];   // [batch-row][k] swizzled
    __shared__ short Bh[32][64], Bl[32][64];   // [gate-col][k] swizzled
    __shared__ float Gs[32][33];

    const int tid = threadIdx.x;
    const int lane = tid & 63;
    const int wv = tid >> 6;                    // wave 0..3
    const int mr = (wv & 1) * 16;               // wave's 16-row quadrant
    const int nc = (wv >> 1) * 16;              // wave's 16-col quadrant
    const int lr = lane & 15;
    const int kg = (lane >> 4) * 8;             // k-group base (0,8,16,24)

    // staging role: 32 rows/cols x 8 k-octets
    const int srow = tid >> 3;                  // 0..31
    const int skq = (tid & 7) * 8;              // 0,8,...,56
    const int bg_s = b0 + srow;

    f32x4 acc = {0.f, 0.f, 0.f, 0.f};
    const int kmax = (t == 0) ? IN_ : 1024;     // h_{-1}=0: skip recurrent half

    for (int k0 = 0; k0 < kmax; k0 += 64) {
        const int kk = k0 + skq;
        // ---- load A-octet (hi/lo bf16) ----
        short8 ahi, alo;
        if (layer == 0 && kk < IN_) {
            const float* xr = x + ((size_t)bg_s * T_ + t) * IN_ + kk;
            float4 f0 = *(const float4*)xr;
            float4 f1 = *(const float4*)(xr + 4);
            float vv[8] = {f0.x, f0.y, f0.z, f0.w, f1.x, f1.y, f1.z, f1.w};
            #pragma unroll
            for (int j = 0; j < 8; ++j) {
                unsigned short hb = f2bf(vv[j]);
                ahi[j] = (short)hb;
                alo[j] = (short)f2bf(vv[j] - bf2f(hb));
            }
        } else {
            const short *sh, *sl;
            size_t off;
            if (kk < IN_) {   // layer1 input = h0 at same t
                off = ((size_t)bg_s * T_ + t) * H_ + kk;
                sh = h0h; sl = h0l;
            } else {          // recurrent h at t-1 (t>0 guaranteed by kmax)
                off = ((size_t)bg_s * T_ + (t - 1)) * H_ + (kk - IN_);
                sh = layer ? h1h : h0h;
                sl = layer ? h1l : h0l;
            }
            ahi = *(const short8*)(sh + off);
            alo = *(const short8*)(sl + off);
        }
        // ---- load B-octet (weights, pre-split) ----
        const size_t woff = (size_t)(n0 + srow) * 1024 + kk;
        short8 bhi = *(const short8*)(Wh + woff);
        short8 blo = *(const short8*)(Wl + woff);

        __syncthreads();   // previous chunk's fragment reads complete
        *(short8*)&Ah[srow][SWZ(srow, skq)] = ahi;
        *(short8*)&Al[srow][SWZ(srow, skq)] = alo;
        *(short8*)&Bh[srow][SWZ(srow, skq)] = bhi;
        *(short8*)&Bl[srow][SWZ(srow, skq)] = blo;
        __syncthreads();

        #pragma unroll
        for (int ks = 0; ks < 2; ++ks) {
            const int kb = ks * 32 + kg;
            short8 a_h = *(const short8*)&Ah[mr + lr][SWZ(mr + lr, kb)];
            short8 a_l = *(const short8*)&Al[mr + lr][SWZ(mr + lr, kb)];
            short8 b_h = *(const short8*)&Bh[nc + lr][SWZ(nc + lr, kb)];
            short8 b_l = *(const short8*)&Bl[nc + lr][SWZ(nc + lr, kb)];
            acc = __builtin_amdgcn_mfma_f32_16x16x32_bf16(as_bf(a_h), as_bf(b_h), acc, 0, 0, 0);
            acc = __builtin_amdgcn_mfma_f32_16x16x32_bf16(as_bf(a_h), as_bf(b_l), acc, 0, 0, 0);
            acc = __builtin_amdgcn_mfma_f32_16x16x32_bf16(as_bf(a_l), as_bf(b_h), acc, 0, 0, 0);
        }
    }

    // C/D layout (verified m89/m91): col = lane&15, row = (lane>>4)*4 + reg
    __syncthreads();
    #pragma unroll
    for (int j = 0; j < 4; ++j)
        Gs[mr + (lane >> 4) * 4 + j][nc + lr] = acc[j];
    __syncthreads();

    // cell update: 32 rows x 8 units (32 gate-cols / 4)
    const int r = tid >> 3, u = tid & 7;
    const int bg = b0 + r;
    const int ug = (n0 >> 2) + u;
    const float gi = Gs[r][4 * u + 0] + bcp[n0 + 4 * u + 0];
    const float gf = Gs[r][4 * u + 1] + bcp[n0 + 4 * u + 1];
    const float gg = Gs[r][4 * u + 2] + bcp[n0 + 4 * u + 2];
    const float go = Gs[r][4 * u + 3] + bcp[n0 + 4 * u + 3];
    const float i_ = sigm(gi), f_ = sigm(gf), g_ = tanh_f(gg), o_ = sigm(go);
    const float cold = (t > 0) ? cst[bg * H_ + ug] : 0.f;
    const float cn = f_ * cold + i_ * g_;
    const float hn = o_ * tanh_f(cn);
    cst[bg * H_ + ug] = cn;
    short* hh = layer ? h1h : h0h;
    short* hl = layer ? h1l : h0l;
    const unsigned short hb = f2bf(hn);
    hh[((size_t)bg * T_ + t) * H_ + ug] = (short)hb;
    hl[((size_t)bg * T_ + t) * H_ + ug] = (short)f2bf(hn - bf2f(hb));
}

// logits[b,t,c] = sigmoid(dot(h1[b,t,:], Wl[c,:]) + bl[c]); h1 is split bf16.
__global__ __launch_bounds__(256) void linear_sig(
    const short* __restrict__ hh, const short* __restrict__ hl,
    const float* __restrict__ Wl, const float* __restrict__ bl,
    float* __restrict__ out)
{
    __shared__ float Ast[32][68];
    __shared__ float Bst[32][68];

    const int tid = threadIdx.x;
    const int tx = tid & 15, ty = tid >> 4;
    const int m0 = blockIdx.x * 64;

    float acc[4][4] = {};

    const int lr = tid >> 2;          // 0..63
    const int lk = (tid & 3) << 3;    // 0,8,16,24
    const int m = m0 + lr;
    const int b = m / 255, tt = m % 255;
    const size_t hbase = ((size_t)b * T_ + tt) * H_;
    const float* wrow = Wl + (size_t)lr * 512;

    for (int k0 = 0; k0 < 512; k0 += 32) {
        short8 h8 = *(const short8*)(hh + hbase + k0 + lk);
        short8 l8 = *(const short8*)(hl + hbase + k0 + lk);
        float av[8];
        #pragma unroll
        for (int j = 0; j < 8; ++j)
            av[j] = bf2f((unsigned short)h8[j]) + bf2f((unsigned short)l8[j]);
        float4 w0 = *(const float4*)(wrow + k0 + lk);
        float4 w1 = *(const float4*)(wrow + k0 + lk + 4);
        __syncthreads();
        #pragma unroll
        for (int j = 0; j < 8; ++j) Ast[lk + j][lr] = av[j];
        Bst[lk + 0][lr] = w0.x; Bst[lk + 1][lr] = w0.y;
        Bst[lk + 2][lr] = w0.z; Bst[lk + 3][lr] = w0.w;
        Bst[lk + 4][lr] = w1.x; Bst[lk + 5][lr] = w1.y;
        Bst[lk + 6][lr] = w1.z; Bst[lk + 7][lr] = w1.w;
        __syncthreads();
        #pragma unroll
        for (int k = 0; k < 32; ++k) {
            float4 av4 = *(const float4*)&Ast[k][4 * ty];
            float4 wv4 = *(const float4*)&Bst[k][4 * tx];
            float ar[4] = {av4.x, av4.y, av4.z, av4.w};
            float wr[4] = {wv4.x, wv4.y, wv4.z, wv4.w};
            #pragma unroll
            for (int i = 0; i < 4; ++i)
                #pragma unroll
                for (int j = 0; j < 4; ++j)
                    acc[i][j] += ar[i] * wr[j];
        }
    }

    const float4 blv = *(const float4*)&bl[4 * tx];
    const float blr[4] = {blv.x, blv.y, blv.z, blv.w};
    #pragma unroll
    for (int i = 0; i < 4; ++i) {
        const int mg = m0 + 4 * ty + i;
        float4 o;
        o.x = sigm(acc[i][0] + blr[0]);
        o.y = sigm(acc[i][1] + blr[1]);
        o.z = sigm(acc[i][2] + blr[2]);
        o.w = sigm(acc[i][3] + blr[3]);
        *(float4*)&out[(size_t)mg * C_ + 4 * tx] = o;
    }
}

extern "C" void kernel_launch(void* const* d_in, const int* in_sizes, int n_in,
                              void* d_out, int out_size, void* d_ws, size_t ws_size,
                              hipStream_t stream)
{
    (void)in_sizes; (void)n_in; (void)out_size; (void)ws_size;

    const float* x    = (const float*)d_in[0];
    const float* Wih0 = (const float*)d_in[3];
    const float* Whh0 = (const float*)d_in[4];
    const float* bih0 = (const float*)d_in[5];
    const float* bhh0 = (const float*)d_in[6];
    const float* Wih1 = (const float*)d_in[7];
    const float* Whh1 = (const float*)d_in[8];
    const float* bih1 = (const float*)d_in[9];
    const float* bhh1 = (const float*)d_in[10];
    const float* Wlin = (const float*)d_in[11];
    const float* blin = (const float*)d_in[12];
    float* out = (float*)d_out;

    // workspace carve (~151 MB)
    char* p = (char*)d_ws;
    auto carve = [&](size_t bytes) { char* r = p; p += (bytes + 255) & ~(size_t)255; return r; };
    short* W0h = (short*)carve((size_t)G4 * 1024 * 2);   // 4 MB each
    short* W0l = (short*)carve((size_t)G4 * 1024 * 2);
    short* W1h = (short*)carve((size_t)G4 * 1024 * 2);
    short* W1l = (short*)carve((size_t)G4 * 1024 * 2);
    float* bc0 = (float*)carve(G4 * 4);
    float* bc1 = (float*)carve(G4 * 4);
    float* c0  = (float*)carve((size_t)B_ * H_ * 4);
    float* c1  = (float*)carve((size_t)B_ * H_ * 4);
    short* h0h = (short*)carve((size_t)B_ * T_ * H_ * 2);  // 33.5 MB each
    short* h0l = (short*)carve((size_t)B_ * T_ * H_ * 2);
    short* h1h = (short*)carve((size_t)B_ * T_ * H_ * 2);
    short* h1l = (short*)carve((size_t)B_ * T_ * H_ * 2);

    prep_w<<<8192, 256, 0, stream>>>(Wih0, Whh0, bih0, bhh0, W0h, W0l, bc0);
    prep_w<<<8192, 256, 0, stream>>>(Wih1, Whh1, bih1, bhh1, W1h, W1l, bc1);

    for (int k = 0; k <= T_; ++k)
        lstm_step_mfma<<<512, 256, 0, stream>>>(x, h0h, h0l, h1h, h1l, c0, c1,
                                                W0h, W0l, W1h, W1l, bc0, bc1, k);

    linear_sig<<<510, 256, 0, stream>>>(h1h, h1l, Wlin, blin, out);
}